// Round 1
// baseline (317.165 us; speedup 1.0000x reference)
//
#include <hip/hip_runtime.h>
#include <cstdint>

#define TT 4096
#define BB 256
#define ID 128

typedef float f32x4 __attribute__((ext_vector_type(4)));
typedef short s16x8 __attribute__((ext_vector_type(8)));

__device__ __forceinline__ float rcp_fast(float x) { return __builtin_amdgcn_rcpf(x); }
__device__ __forceinline__ float sigm(float x) { return rcp_fast(1.0f + __expf(-x)); }
__device__ __forceinline__ float tanh_fast(float x) {
  float e = __expf(2.0f * x);          // large +x -> inf -> 1; large -x -> 0 -> -1
  return 1.0f - 2.0f * rcp_fast(e + 1.0f);
}

union U16B { uint32_t u[4]; s16x8 v; };

// Split 8 f32 into bf16-hi (truncate) + bf16-lo (exact residual, truncated).
// x = hi + rest exactly up to rest's own 2^-16; 3-product GEMM error ~1e-4.
__device__ __forceinline__ void split8(const float4 a, const float4 b,
                                       s16x8& hi, s16x8& lo) {
  uint32_t a0 = __float_as_uint(a.x), a1 = __float_as_uint(a.y);
  uint32_t a2 = __float_as_uint(a.z), a3 = __float_as_uint(a.w);
  uint32_t b0 = __float_as_uint(b.x), b1 = __float_as_uint(b.y);
  uint32_t b2 = __float_as_uint(b.z), b3 = __float_as_uint(b.w);
  U16B h;
  h.u[0] = (a0 >> 16) | (a1 & 0xffff0000u);
  h.u[1] = (a2 >> 16) | (a3 & 0xffff0000u);
  h.u[2] = (b0 >> 16) | (b1 & 0xffff0000u);
  h.u[3] = (b2 >> 16) | (b3 & 0xffff0000u);
  hi = h.v;
  float r0 = a.x - __uint_as_float(a0 & 0xffff0000u);
  float r1 = a.y - __uint_as_float(a1 & 0xffff0000u);
  float r2 = a.z - __uint_as_float(a2 & 0xffff0000u);
  float r3 = a.w - __uint_as_float(a3 & 0xffff0000u);
  float r4 = b.x - __uint_as_float(b0 & 0xffff0000u);
  float r5 = b.y - __uint_as_float(b1 & 0xffff0000u);
  float r6 = b.z - __uint_as_float(b2 & 0xffff0000u);
  float r7 = b.w - __uint_as_float(b3 & 0xffff0000u);
  U16B l;
  l.u[0] = (__float_as_uint(r0) >> 16) | (__float_as_uint(r1) & 0xffff0000u);
  l.u[1] = (__float_as_uint(r2) >> 16) | (__float_as_uint(r3) & 0xffff0000u);
  l.u[2] = (__float_as_uint(r4) >> 16) | (__float_as_uint(r5) & 0xffff0000u);
  l.u[3] = (__float_as_uint(r6) >> 16) | (__float_as_uint(r7) & 0xffff0000u);
  lo = l.v;
}

// gates via MFMA, LDS-free: block = 64 flat rows (t,b), 256 thr = 4 waves.
// Wave w computes rows w*16..+15 x all 32 gates with mfma_f32_16x16x32_bf16,
// 3-product split-bf16 for fp32 accuracy. A-fragments load DIRECT from global
// (each wave owns its 16 rows; lanes {i,i+16,i+32,i+48} share a 128B line so
// L1 absorbs the sector split). B-fragments (W_ih, 16 KB, L2-resident) load
// direct too. No LDS, no barrier -> occupancy is VGPR-bound streaming.
//
// xg output layout (permuted for the rnn's float4 loads):
//   float idx = row*32 + j*4 + gtype   (row = t*256+b, j = g&7, gtype = g>>3)
// so the rnn's lane (b,j) reads one float4 = (i,f,g,o) for hidden unit j.
__global__ __launch_bounds__(256) void gates_kernel(
    const float* __restrict__ x, const float* __restrict__ W_ih,
    const float* __restrict__ b_ih, const float* __restrict__ b_hh,
    float* __restrict__ xg)
{
  const int tid  = threadIdx.x;
  const int lane = tid & 63;
  const int wv   = tid >> 6;
  const size_t row0 = (size_t)blockIdx.x * 64;
  const int rloc = wv * 16 + (lane & 15);    // A-frag row (local)
  const int kq   = (lane >> 4) * 2;          // quad offset of this lane's k-chunk

  const float4* __restrict__ x4 = reinterpret_cast<const float4*>(x);
  const float4* __restrict__ w4 = reinterpret_cast<const float4*>(W_ih);

  // B fragments: lane holds W[g][k..k+7] for g = nf*16 + (lane&15)
  s16x8 Bh[4][2], Bl[4][2];
#pragma unroll
  for (int kc = 0; kc < 4; ++kc) {
#pragma unroll
    for (int nf = 0; nf < 2; ++nf) {
      int g  = nf * 16 + (lane & 15);
      int q0 = kc * 8 + kq;
      float4 wa = w4[g * 32 + q0];
      float4 wb = w4[g * 32 + q0 + 1];
      split8(wa, wb, Bh[kc][nf], Bl[kc][nf]);
    }
  }

  f32x4 acc[2] = {{0.f, 0.f, 0.f, 0.f}, {0.f, 0.f, 0.f, 0.f}};
  const size_t xbase = (row0 + (size_t)rloc) * 32;   // in float4 units
#pragma unroll
  for (int kc = 0; kc < 4; ++kc) {
    int q0 = kc * 8 + kq;
    float4 xa = x4[xbase + q0];
    float4 xb = x4[xbase + q0 + 1];
    s16x8 Ah, Al;
    split8(xa, xb, Ah, Al);
#pragma unroll
    for (int nf = 0; nf < 2; ++nf) {
      acc[nf] = __builtin_amdgcn_mfma_f32_16x16x32_bf16(Ah, Bh[kc][nf], acc[nf], 0, 0, 0);
      acc[nf] = __builtin_amdgcn_mfma_f32_16x16x32_bf16(Ah, Bl[kc][nf], acc[nf], 0, 0, 0);
      acc[nf] = __builtin_amdgcn_mfma_f32_16x16x32_bf16(Al, Bh[kc][nf], acc[nf], 0, 0, 0);
    }
  }

  // C/D: col = lane&15, row = (lane>>4)*4 + reg  [m89-verified]
#pragma unroll
  for (int nf = 0; nf < 2; ++nf) {
    int g = nf * 16 + (lane & 15);
    float bo = b_ih[g] + b_hh[g];
    int off = (g & 7) * 4 + (g >> 3);            // permuted column
    size_t rowg = row0 + wv * 16 + (lane >> 4) * 4;
#pragma unroll
    for (int reg = 0; reg < 4; ++reg) {
      xg[(rowg + reg) * 32 + off] = acc[nf][reg] + bo;
    }
  }
}

// rnn: 1-wave blocks, grid (33 segments, 32 batch-chunks of 8).
// Lane = (b-sub, j). Deep register prefetch: 8-step chunks, double-buffered,
// static indexing only. One coalesced float4 load per step (i,f,g,o for this
// lane's (b,j)) thanks to the permuted xg layout.
__global__ __launch_bounds__(64) void rnn_kernel(
    const float* __restrict__ xg, const int* __restrict__ reset_idx,
    const float* __restrict__ W_hh, const float* __restrict__ W_proj,
    const float* __restrict__ b_proj, float* __restrict__ out)
{
  const int seg  = blockIdx.x;          // 0..32
  const int lane = threadIdx.x;
  const int j    = lane & 7;
  const int b    = blockIdx.y * 8 + (lane >> 3);

  const int start = (seg == 0)  ? 0  : reset_idx[seg - 1];
  const int end   = (seg == 32) ? TT : reset_idx[seg];
  if (start >= end) return;

  float wi[8], wf[8], wg_[8], wo[8];
#pragma unroll
  for (int k = 0; k < 8; ++k) {
    wi[k]  = W_hh[(0  + j) * 8 + k];
    wf[k]  = W_hh[(8  + j) * 8 + k];
    wg_[k] = W_hh[(16 + j) * 8 + k];
    wo[k]  = W_hh[(24 + j) * 8 + k];
  }
  const float bp = b_proj[0];
  float wp[8];
#pragma unroll
  for (int k = 0; k < 8; ++k) wp[k] = W_proj[k];

  float h[8];
#pragma unroll
  for (int k = 0; k < 8; ++k) h[k] = 0.f;
  float c = 0.f;

  float* __restrict__ vout = out;                    // value   [T*B]
  float* __restrict__ hout = out + (size_t)TT * BB;  // rnn_out [T*B*8]

  const float4* __restrict__ xg4 = reinterpret_cast<const float4*>(xg);
  const size_t lbase = (size_t)b * 8 + j;            // + t*2048

  float4 bufA[8], bufB[8];

#define LOADC(buf, tc) do {                                                  \
  _Pragma("unroll")                                                          \
  for (int s = 0; s < 8; ++s) {                                              \
    int tt = (tc) + s; tt = tt < TT ? tt : TT - 1;   /* clamp: always valid */\
    (buf)[s] = xg4[(size_t)tt * 2048 + lbase];                               \
  }                                                                          \
} while (0)

#define STEP8(buf, tc) do {                                                  \
  _Pragma("unroll")                                                          \
  for (int s = 0; s < 8; ++s) {                                              \
    int t = (tc) + s;                                                        \
    if (t < end) {       /* wave-uniform branch */                           \
      float gi = (buf)[s].x, gf = (buf)[s].y;                                \
      float gg = (buf)[s].z, go = (buf)[s].w;                                \
      float gi1 = 0.f, gf1 = 0.f, gg1 = 0.f, go1 = 0.f;                      \
      _Pragma("unroll")                                                      \
      for (int k = 0; k < 8; k += 2) {                                       \
        gi += wi[k]  * h[k];  gi1 += wi[k+1]  * h[k+1];                      \
        gf += wf[k]  * h[k];  gf1 += wf[k+1]  * h[k+1];                      \
        gg += wg_[k] * h[k];  gg1 += wg_[k+1] * h[k+1];                      \
        go += wo[k]  * h[k];  go1 += wo[k+1]  * h[k+1];                      \
      }                                                                      \
      gi += gi1; gf += gf1; gg += gg1; go += go1;                            \
      float si = sigm(gi), sf = sigm(gf), sg = tanh_fast(gg), so = sigm(go); \
      c = sf * c + si * sg;                                                  \
      float hj = so * tanh_fast(c);                                          \
      hout[((size_t)t * BB + b) * 8 + j] = hj;                               \
      _Pragma("unroll")                                                      \
      for (int k = 0; k < 8; ++k) h[k] = __shfl(hj, k, 8);                   \
      float sv = bp;                                                         \
      _Pragma("unroll")                                                      \
      for (int k = 0; k < 8; ++k) sv += wp[k] * h[k];                        \
      if (j == 0) vout[(size_t)t * BB + b] = sv;                             \
    }                                                                        \
  }                                                                          \
} while (0)

  LOADC(bufA, start);
  LOADC(bufB, start + 8);
  for (int tc = start; tc < end; tc += 16) {
    STEP8(bufA, tc);
    LOADC(bufA, tc + 16);      // ~8 steps ahead of use
    STEP8(bufB, tc + 8);
    LOADC(bufB, tc + 24);
  }
#undef LOADC
#undef STEP8
}

extern "C" void kernel_launch(void* const* d_in, const int* in_sizes, int n_in,
                              void* d_out, int out_size, void* d_ws, size_t ws_size,
                              hipStream_t stream) {
  const float* x      = (const float*)d_in[0];
  const int*   ridx   = (const int*)  d_in[1];
  const float* W_ih   = (const float*)d_in[2];
  const float* W_hh   = (const float*)d_in[3];
  const float* b_ih   = (const float*)d_in[4];
  const float* b_hh   = (const float*)d_in[5];
  const float* W_proj = (const float*)d_in[6];
  const float* b_proj = (const float*)d_in[7];
  float* out = (float*)d_out;
  float* xg  = (float*)d_ws;   // T*B*32 f32 = 128 MiB

  gates_kernel<<<(TT * BB) / 64, 256, 0, stream>>>(x, W_ih, b_ih, b_hh, xg);
  rnn_kernel<<<dim3(33, 32), 64, 0, stream>>>(xg, ridx, W_hh, W_proj, b_proj, out);
}

// Round 3
// 289.852 us; speedup vs baseline: 1.0942x; 1.0942x over previous
//
#include <hip/hip_runtime.h>
#include <cstdint>

#define TT 4096
#define BB 256
#define ID 128

typedef float f32x4 __attribute__((ext_vector_type(4)));
typedef short s16x8 __attribute__((ext_vector_type(8)));

__device__ __forceinline__ float rcp_fast(float x) { return __builtin_amdgcn_rcpf(x); }
__device__ __forceinline__ float sigm(float x) { return rcp_fast(1.0f + __expf(-x)); }
__device__ __forceinline__ float tanh_fast(float x) {
  float e = __expf(2.0f * x);          // large +x -> inf -> 1; large -x -> 0 -> -1
  return 1.0f - 2.0f * rcp_fast(e + 1.0f);
}

union U16B { uint32_t u[4]; s16x8 v; };

// Split 8 f32 into bf16-hi (truncate) + bf16-lo (exact residual, truncated).
// x = hi + rest exactly up to rest's own 2^-16; 3-product GEMM error ~1e-4.
__device__ __forceinline__ void split8(const float4 a, const float4 b,
                                       s16x8& hi, s16x8& lo) {
  uint32_t a0 = __float_as_uint(a.x), a1 = __float_as_uint(a.y);
  uint32_t a2 = __float_as_uint(a.z), a3 = __float_as_uint(a.w);
  uint32_t b0 = __float_as_uint(b.x), b1 = __float_as_uint(b.y);
  uint32_t b2 = __float_as_uint(b.z), b3 = __float_as_uint(b.w);
  U16B h;
  h.u[0] = (a0 >> 16) | (a1 & 0xffff0000u);
  h.u[1] = (a2 >> 16) | (a3 & 0xffff0000u);
  h.u[2] = (b0 >> 16) | (b1 & 0xffff0000u);
  h.u[3] = (b2 >> 16) | (b3 & 0xffff0000u);
  hi = h.v;
  float r0 = a.x - __uint_as_float(a0 & 0xffff0000u);
  float r1 = a.y - __uint_as_float(a1 & 0xffff0000u);
  float r2 = a.z - __uint_as_float(a2 & 0xffff0000u);
  float r3 = a.w - __uint_as_float(a3 & 0xffff0000u);
  float r4 = b.x - __uint_as_float(b0 & 0xffff0000u);
  float r5 = b.y - __uint_as_float(b1 & 0xffff0000u);
  float r6 = b.z - __uint_as_float(b2 & 0xffff0000u);
  float r7 = b.w - __uint_as_float(b3 & 0xffff0000u);
  U16B l;
  l.u[0] = (__float_as_uint(r0) >> 16) | (__float_as_uint(r1) & 0xffff0000u);
  l.u[1] = (__float_as_uint(r2) >> 16) | (__float_as_uint(r3) & 0xffff0000u);
  l.u[2] = (__float_as_uint(r4) >> 16) | (__float_as_uint(r5) & 0xffff0000u);
  l.u[3] = (__float_as_uint(r6) >> 16) | (__float_as_uint(r7) & 0xffff0000u);
  lo = l.v;
}

// gates via MFMA: block = 64 flat rows (t,b), 256 thr = 4 waves.
// x tile staged in LDS (32 KB, f4-quad XOR swizzle). W_ih (16 KB, L2-resident)
// loads DIRECT to VGPR B-fragments once per block (no wt LDS -> 48->32 KB,
// occupancy 3->5 blocks/CU).
//
// Permuted-B trick: output column m = nf*16 + (lane&15) of the MFMA holds
// x . W[g'] for WHICHEVER row g' that lane loaded. We want xg layout
//   float col m  <->  gate g' = (m&3)*8 + (m>>2)   (i.e. [j][comp], comp=i,f,g,o)
// so lane (nf,c) simply loads W[g'] and adds bias b[g']. The store is then the
// plain contiguous round-0 pattern xg[row*32 + m] and the rnn reads one
// float4 (i,f,g,o) per (b,j). No cross-lane exchange anywhere.
__global__ __launch_bounds__(256) void gates_kernel(
    const float* __restrict__ x, const float* __restrict__ W_ih,
    const float* __restrict__ b_ih, const float* __restrict__ b_hh,
    float* __restrict__ xg)
{
  __shared__ float4 xt[64 * 32];   // 32 KB  [row][q ^ (row&31)]
  const int tid = threadIdx.x;
  const size_t row0 = (size_t)blockIdx.x * 64;

  const float4* __restrict__ src = reinterpret_cast<const float4*>(x) + row0 * 32;
#pragma unroll
  for (int it = 0; it < 8; ++it) {           // 2048 f4, coalesced
    int idx = it * 256 + tid;
    int r = idx >> 5, q = idx & 31;
    xt[r * 32 + (q ^ (r & 31))] = src[idx];
  }

  const int lane = tid & 63;
  const int wv   = tid >> 6;
  const int rloc = wv * 16 + (lane & 15);    // A-frag row (local)
  const int kq   = (lane >> 4) * 2;          // quad offset of this lane's k-chunk

  // B fragments direct from global, permuted row choice (see header comment).
  // One-time setup; overlaps the x staging above (no LDS dependency).
  const float4* __restrict__ w4 = reinterpret_cast<const float4*>(W_ih);
  int gp[2];   float bo[2];
#pragma unroll
  for (int nf = 0; nf < 2; ++nf) {
    int m  = nf * 16 + (lane & 15);
    gp[nf] = (m & 3) * 8 + (m >> 2);         // gate whose result lands at col m
    bo[nf] = b_ih[gp[nf]] + b_hh[gp[nf]];
  }
  s16x8 Bh[4][2], Bl[4][2];
#pragma unroll
  for (int kc = 0; kc < 4; ++kc) {
#pragma unroll
    for (int nf = 0; nf < 2; ++nf) {
      int q0 = kc * 8 + kq;
      float4 wa = w4[gp[nf] * 32 + q0];
      float4 wb = w4[gp[nf] * 32 + q0 + 1];
      split8(wa, wb, Bh[kc][nf], Bl[kc][nf]);
    }
  }

  __syncthreads();

  f32x4 acc[2] = {{0.f, 0.f, 0.f, 0.f}, {0.f, 0.f, 0.f, 0.f}};
#pragma unroll
  for (int kc = 0; kc < 4; ++kc) {
    int q0 = kc * 8 + kq;
    float4 xa = xt[rloc * 32 + (q0 ^ (rloc & 31))];
    float4 xb = xt[rloc * 32 + ((q0 + 1) ^ (rloc & 31))];
    s16x8 Ah, Al;
    split8(xa, xb, Ah, Al);
#pragma unroll
    for (int nf = 0; nf < 2; ++nf) {
      acc[nf] = __builtin_amdgcn_mfma_f32_16x16x32_bf16(Ah, Bh[kc][nf], acc[nf], 0, 0, 0);
      acc[nf] = __builtin_amdgcn_mfma_f32_16x16x32_bf16(Ah, Bl[kc][nf], acc[nf], 0, 0, 0);
      acc[nf] = __builtin_amdgcn_mfma_f32_16x16x32_bf16(Al, Bh[kc][nf], acc[nf], 0, 0, 0);
    }
  }

  // C/D: col = lane&15, row = (lane>>4)*4 + reg  [m89-verified]
  // Store straight to col m = nf*16 + (lane&15): contiguous across the
  // 16-lane group, 4 row-groups per instruction (round-0 verified pattern).
#pragma unroll
  for (int nf = 0; nf < 2; ++nf) {
    int m = nf * 16 + (lane & 15);
    size_t rowg = row0 + wv * 16 + (lane >> 4) * 4;
#pragma unroll
    for (int reg = 0; reg < 4; ++reg) {
      xg[(rowg + reg) * 32 + m] = acc[nf][reg] + bo[nf];
    }
  }
}

// rnn: 1-wave blocks, grid (33 segments, 32 batch-chunks of 8).
// Lane = (b-sub, j). Deep register prefetch: 8-step chunks, double-buffered,
// static indexing only. One coalesced float4 load per step (i,f,g,o for this
// lane's (b,j)) thanks to the permuted xg layout — wave reads 1 KiB contiguous.
__global__ __launch_bounds__(64) void rnn_kernel(
    const float* __restrict__ xg, const int* __restrict__ reset_idx,
    const float* __restrict__ W_hh, const float* __restrict__ W_proj,
    const float* __restrict__ b_proj, float* __restrict__ out)
{
  const int seg  = blockIdx.x;          // 0..32
  const int lane = threadIdx.x;
  const int j    = lane & 7;
  const int b    = blockIdx.y * 8 + (lane >> 3);

  const int start = (seg == 0)  ? 0  : reset_idx[seg - 1];
  const int end   = (seg == 32) ? TT : reset_idx[seg];
  if (start >= end) return;

  float wi[8], wf[8], wg_[8], wo[8];
#pragma unroll
  for (int k = 0; k < 8; ++k) {
    wi[k]  = W_hh[(0  + j) * 8 + k];
    wf[k]  = W_hh[(8  + j) * 8 + k];
    wg_[k] = W_hh[(16 + j) * 8 + k];
    wo[k]  = W_hh[(24 + j) * 8 + k];
  }
  const float bp = b_proj[0];
  float wp[8];
#pragma unroll
  for (int k = 0; k < 8; ++k) wp[k] = W_proj[k];

  float h[8];
#pragma unroll
  for (int k = 0; k < 8; ++k) h[k] = 0.f;
  float c = 0.f;

  float* __restrict__ vout = out;                    // value   [T*B]
  float* __restrict__ hout = out + (size_t)TT * BB;  // rnn_out [T*B*8]

  const float4* __restrict__ xg4 = reinterpret_cast<const float4*>(xg);
  const size_t lbase = (size_t)b * 8 + j;            // + t*2048

  float4 bufA[8], bufB[8];

#define LOADC(buf, tc) do {                                                  \
  _Pragma("unroll")                                                          \
  for (int s = 0; s < 8; ++s) {                                              \
    int tt = (tc) + s; tt = tt < TT ? tt : TT - 1;   /* clamp: always valid */\
    (buf)[s] = xg4[(size_t)tt * 2048 + lbase];                               \
  }                                                                          \
} while (0)

#define STEP8(buf, tc) do {                                                  \
  _Pragma("unroll")                                                          \
  for (int s = 0; s < 8; ++s) {                                              \
    int t = (tc) + s;                                                        \
    if (t < end) {       /* wave-uniform branch */                           \
      float gi = (buf)[s].x, gf = (buf)[s].y;                                \
      float gg = (buf)[s].z, go = (buf)[s].w;                                \
      float gi1 = 0.f, gf1 = 0.f, gg1 = 0.f, go1 = 0.f;                      \
      _Pragma("unroll")                                                      \
      for (int k = 0; k < 8; k += 2) {                                       \
        gi += wi[k]  * h[k];  gi1 += wi[k+1]  * h[k+1];                      \
        gf += wf[k]  * h[k];  gf1 += wf[k+1]  * h[k+1];                      \
        gg += wg_[k] * h[k];  gg1 += wg_[k+1] * h[k+1];                      \
        go += wo[k]  * h[k];  go1 += wo[k+1]  * h[k+1];                      \
      }                                                                      \
      gi += gi1; gf += gf1; gg += gg1; go += go1;                            \
      float si = sigm(gi), sf = sigm(gf), sg = tanh_fast(gg), so = sigm(go); \
      c = sf * c + si * sg;                                                  \
      float hj = so * tanh_fast(c);                                          \
      hout[((size_t)t * BB + b) * 8 + j] = hj;                               \
      _Pragma("unroll")                                                      \
      for (int k = 0; k < 8; ++k) h[k] = __shfl(hj, k, 8);                   \
      float sv = bp;                                                         \
      _Pragma("unroll")                                                      \
      for (int k = 0; k < 8; ++k) sv += wp[k] * h[k];                        \
      if (j == 0) vout[(size_t)t * BB + b] = sv;                             \
    }                                                                        \
  }                                                                          \
} while (0)

  LOADC(bufA, start);
  LOADC(bufB, start + 8);
  for (int tc = start; tc < end; tc += 16) {
    STEP8(bufA, tc);
    LOADC(bufA, tc + 16);      // ~8 steps ahead of use
    STEP8(bufB, tc + 8);
    LOADC(bufB, tc + 24);
  }
#undef LOADC
#undef STEP8
}

extern "C" void kernel_launch(void* const* d_in, const int* in_sizes, int n_in,
                              void* d_out, int out_size, void* d_ws, size_t ws_size,
                              hipStream_t stream) {
  const float* x      = (const float*)d_in[0];
  const int*   ridx   = (const int*)  d_in[1];
  const float* W_ih   = (const float*)d_in[2];
  const float* W_hh   = (const float*)d_in[3];
  const float* b_ih   = (const float*)d_in[4];
  const float* b_hh   = (const float*)d_in[5];
  const float* W_proj = (const float*)d_in[6];
  const float* b_proj = (const float*)d_in[7];
  float* out = (float*)d_out;
  float* xg  = (float*)d_ws;   // T*B*32 f32 = 128 MiB

  gates_kernel<<<(TT * BB) / 64, 256, 0, stream>>>(x, W_ih, b_ih, b_hh, xg);
  rnn_kernel<<<dim3(33, 32), 64, 0, stream>>>(xg, ridx, W_hh, W_proj, b_proj, out);
}

// Round 4
// 253.829 us; speedup vs baseline: 1.2495x; 1.1419x over previous
//
#include <hip/hip_runtime.h>
#include <cstdint>

#define TT 4096
#define BB 256
#define ID 128

typedef float f32x4 __attribute__((ext_vector_type(4)));
typedef short s16x8 __attribute__((ext_vector_type(8)));

__device__ __forceinline__ float rcp_fast(float x) { return __builtin_amdgcn_rcpf(x); }
__device__ __forceinline__ float sigm(float x) { return rcp_fast(1.0f + __expf(-x)); }
__device__ __forceinline__ float tanh_fast(float x) {
  float e = __expf(2.0f * x);          // large +x -> inf -> 1; large -x -> 0 -> -1
  return 1.0f - 2.0f * rcp_fast(e + 1.0f);
}

union U16B { uint32_t u[4]; s16x8 v; };

// Split 8 f32 into bf16-hi (truncate) + bf16-lo (exact residual, truncated).
// x = hi + rest exactly up to rest's own 2^-16; 3-product GEMM error ~1e-4.
__device__ __forceinline__ void split8(const float4 a, const float4 b,
                                       s16x8& hi, s16x8& lo) {
  uint32_t a0 = __float_as_uint(a.x), a1 = __float_as_uint(a.y);
  uint32_t a2 = __float_as_uint(a.z), a3 = __float_as_uint(a.w);
  uint32_t b0 = __float_as_uint(b.x), b1 = __float_as_uint(b.y);
  uint32_t b2 = __float_as_uint(b.z), b3 = __float_as_uint(b.w);
  U16B h;
  h.u[0] = (a0 >> 16) | (a1 & 0xffff0000u);
  h.u[1] = (a2 >> 16) | (a3 & 0xffff0000u);
  h.u[2] = (b0 >> 16) | (b1 & 0xffff0000u);
  h.u[3] = (b2 >> 16) | (b3 & 0xffff0000u);
  hi = h.v;
  float r0 = a.x - __uint_as_float(a0 & 0xffff0000u);
  float r1 = a.y - __uint_as_float(a1 & 0xffff0000u);
  float r2 = a.z - __uint_as_float(a2 & 0xffff0000u);
  float r3 = a.w - __uint_as_float(a3 & 0xffff0000u);
  float r4 = b.x - __uint_as_float(b0 & 0xffff0000u);
  float r5 = b.y - __uint_as_float(b1 & 0xffff0000u);
  float r6 = b.z - __uint_as_float(b2 & 0xffff0000u);
  float r7 = b.w - __uint_as_float(b3 & 0xffff0000u);
  U16B l;
  l.u[0] = (__float_as_uint(r0) >> 16) | (__float_as_uint(r1) & 0xffff0000u);
  l.u[1] = (__float_as_uint(r2) >> 16) | (__float_as_uint(r3) & 0xffff0000u);
  l.u[2] = (__float_as_uint(r4) >> 16) | (__float_as_uint(r5) & 0xffff0000u);
  l.u[3] = (__float_as_uint(r6) >> 16) | (__float_as_uint(r7) & 0xffff0000u);
  lo = l.v;
}

// One-time prep: build the split-bf16 B fragments for the gates GEMM in FINAL
// fragment order, so the hot kernel's B-load is 16 coalesced 16B/lane reads.
// Permuted-B mapping (R3-verified): output col m holds gate
//   gp = (m&3)*8 + (m>>2)   (xg layout [row][j][comp], comp = i,f,g,o)
// Also packs bo[m] = b_ih[gp]+b_hh[gp].
__global__ __launch_bounds__(64) void prep_kernel(
    const float* __restrict__ W_ih, const float* __restrict__ b_ih,
    const float* __restrict__ b_hh,
    s16x8* __restrict__ whi, s16x8* __restrict__ wlo, float* __restrict__ bo)
{
  const int lane = threadIdx.x;              // 0..63
  const int kq   = (lane >> 4) * 2;
  const float4* __restrict__ w4 = reinterpret_cast<const float4*>(W_ih);
#pragma unroll
  for (int kc = 0; kc < 4; ++kc) {
#pragma unroll
    for (int nf = 0; nf < 2; ++nf) {
      int m  = nf * 16 + (lane & 15);
      int gp = (m & 3) * 8 + (m >> 2);
      int q0 = kc * 8 + kq;
      float4 wa = w4[gp * 32 + q0];
      float4 wb = w4[gp * 32 + q0 + 1];
      s16x8 hi, lo;
      split8(wa, wb, hi, lo);
      whi[(kc * 2 + nf) * 64 + lane] = hi;
      wlo[(kc * 2 + nf) * 64 + lane] = lo;
    }
  }
  if (lane < 32) {
    int gp = (lane & 3) * 8 + (lane >> 2);
    bo[lane] = b_ih[gp] + b_hh[gp];
  }
}

// gates via MFMA: block = 64 flat rows (t,b), 256 thr = 4 waves.
// x tile staged in LDS (32 KB, f4-quad XOR swizzle). B fragments come
// PRE-SPLIT from the prep kernel: 16 coalesced dwordx4 loads (L2-hot 16 KB),
// zero per-block split8 on the B side, no W LDS tile (48->32 KB).
// Store: contiguous col m per 16-lane group (R0/R3-verified address pattern);
// permuted-B makes col m = [j][comp] so the rnn reads one float4 per (b,j).
__global__ __launch_bounds__(256) void gates_kernel(
    const float* __restrict__ x,
    const s16x8* __restrict__ whi, const s16x8* __restrict__ wlo,
    const float* __restrict__ bo, float* __restrict__ xg)
{
  __shared__ float4 xt[64 * 32];   // 32 KB  [row][q ^ (row&31)]
  const int tid = threadIdx.x;
  const size_t row0 = (size_t)blockIdx.x * 64;

  const float4* __restrict__ src = reinterpret_cast<const float4*>(x) + row0 * 32;
#pragma unroll
  for (int it = 0; it < 8; ++it) {           // 2048 f4, coalesced
    int idx = it * 256 + tid;
    int r = idx >> 5, q = idx & 31;
    xt[r * 32 + (q ^ (r & 31))] = src[idx];
  }

  const int lane = tid & 63;
  const int wv   = tid >> 6;
  const int rloc = wv * 16 + (lane & 15);    // A-frag row (local)
  const int kq   = (lane >> 4) * 2;          // quad offset of this lane's k-chunk

  // B fragments: prepacked, fragment-ordered -> each load is 64 lanes x 16B
  // contiguous (1 KiB). Issued before the barrier; overlaps x staging.
  s16x8 Bh[4][2], Bl[4][2];
#pragma unroll
  for (int kc = 0; kc < 4; ++kc) {
#pragma unroll
    for (int nf = 0; nf < 2; ++nf) {
      Bh[kc][nf] = whi[(kc * 2 + nf) * 64 + lane];
      Bl[kc][nf] = wlo[(kc * 2 + nf) * 64 + lane];
    }
  }
  const float bo0 = bo[lane & 15];
  const float bo1 = bo[16 + (lane & 15)];

  __syncthreads();

  f32x4 acc[2] = {{0.f, 0.f, 0.f, 0.f}, {0.f, 0.f, 0.f, 0.f}};
#pragma unroll
  for (int kc = 0; kc < 4; ++kc) {
    int q0 = kc * 8 + kq;
    float4 xa = xt[rloc * 32 + (q0 ^ (rloc & 31))];
    float4 xb = xt[rloc * 32 + ((q0 + 1) ^ (rloc & 31))];
    s16x8 Ah, Al;
    split8(xa, xb, Ah, Al);
#pragma unroll
    for (int nf = 0; nf < 2; ++nf) {
      acc[nf] = __builtin_amdgcn_mfma_f32_16x16x32_bf16(Ah, Bh[kc][nf], acc[nf], 0, 0, 0);
      acc[nf] = __builtin_amdgcn_mfma_f32_16x16x32_bf16(Ah, Bl[kc][nf], acc[nf], 0, 0, 0);
      acc[nf] = __builtin_amdgcn_mfma_f32_16x16x32_bf16(Al, Bh[kc][nf], acc[nf], 0, 0, 0);
    }
  }

  // C/D: col = lane&15, row = (lane>>4)*4 + reg  [m89-verified]
#pragma unroll
  for (int nf = 0; nf < 2; ++nf) {
    int m = nf * 16 + (lane & 15);
    float b = nf ? bo1 : bo0;
    size_t rowg = row0 + wv * 16 + (lane >> 4) * 4;
#pragma unroll
    for (int reg = 0; reg < 4; ++reg) {
      xg[(rowg + reg) * 32 + m] = acc[nf][reg] + b;
    }
  }
}

// rnn: 1-wave blocks, grid (33 segments, 32 batch-chunks of 8).
// Lane = (b-sub, j). Deep register prefetch: 8-step chunks, double-buffered,
// static indexing only. One coalesced float4 load per step (i,f,g,o for this
// lane's (b,j)) thanks to the permuted xg layout — wave reads 1 KiB contiguous.
__global__ __launch_bounds__(64) void rnn_kernel(
    const float* __restrict__ xg, const int* __restrict__ reset_idx,
    const float* __restrict__ W_hh, const float* __restrict__ W_proj,
    const float* __restrict__ b_proj, float* __restrict__ out)
{
  const int seg  = blockIdx.x;          // 0..32
  const int lane = threadIdx.x;
  const int j    = lane & 7;
  const int b    = blockIdx.y * 8 + (lane >> 3);

  const int start = (seg == 0)  ? 0  : reset_idx[seg - 1];
  const int end   = (seg == 32) ? TT : reset_idx[seg];
  if (start >= end) return;

  float wi[8], wf[8], wg_[8], wo[8];
#pragma unroll
  for (int k = 0; k < 8; ++k) {
    wi[k]  = W_hh[(0  + j) * 8 + k];
    wf[k]  = W_hh[(8  + j) * 8 + k];
    wg_[k] = W_hh[(16 + j) * 8 + k];
    wo[k]  = W_hh[(24 + j) * 8 + k];
  }
  const float bp = b_proj[0];
  float wp[8];
#pragma unroll
  for (int k = 0; k < 8; ++k) wp[k] = W_proj[k];

  float h[8];
#pragma unroll
  for (int k = 0; k < 8; ++k) h[k] = 0.f;
  float c = 0.f;

  float* __restrict__ vout = out;                    // value   [T*B]
  float* __restrict__ hout = out + (size_t)TT * BB;  // rnn_out [T*B*8]

  const float4* __restrict__ xg4 = reinterpret_cast<const float4*>(xg);
  const size_t lbase = (size_t)b * 8 + j;            // + t*2048

  float4 bufA[8], bufB[8];

#define LOADC(buf, tc) do {                                                  \
  _Pragma("unroll")                                                          \
  for (int s = 0; s < 8; ++s) {                                              \
    int tt = (tc) + s; tt = tt < TT ? tt : TT - 1;   /* clamp: always valid */\
    (buf)[s] = xg4[(size_t)tt * 2048 + lbase];                               \
  }                                                                          \
} while (0)

#define STEP8(buf, tc) do {                                                  \
  _Pragma("unroll")                                                          \
  for (int s = 0; s < 8; ++s) {                                              \
    int t = (tc) + s;                                                        \
    if (t < end) {       /* wave-uniform branch */                           \
      float gi = (buf)[s].x, gf = (buf)[s].y;                                \
      float gg = (buf)[s].z, go = (buf)[s].w;                                \
      float gi1 = 0.f, gf1 = 0.f, gg1 = 0.f, go1 = 0.f;                      \
      _Pragma("unroll")                                                      \
      for (int k = 0; k < 8; k += 2) {                                       \
        gi += wi[k]  * h[k];  gi1 += wi[k+1]  * h[k+1];                      \
        gf += wf[k]  * h[k];  gf1 += wf[k+1]  * h[k+1];                      \
        gg += wg_[k] * h[k];  gg1 += wg_[k+1] * h[k+1];                      \
        go += wo[k]  * h[k];  go1 += wo[k+1]  * h[k+1];                      \
      }                                                                      \
      gi += gi1; gf += gf1; gg += gg1; go += go1;                            \
      float si = sigm(gi), sf = sigm(gf), sg = tanh_fast(gg), so = sigm(go); \
      c = sf * c + si * sg;                                                  \
      float hj = so * tanh_fast(c);                                          \
      hout[((size_t)t * BB + b) * 8 + j] = hj;                               \
      _Pragma("unroll")                                                      \
      for (int k = 0; k < 8; ++k) h[k] = __shfl(hj, k, 8);                   \
      float sv = bp;                                                         \
      _Pragma("unroll")                                                      \
      for (int k = 0; k < 8; ++k) sv += wp[k] * h[k];                        \
      if (j == 0) vout[(size_t)t * BB + b] = sv;                             \
    }                                                                        \
  }                                                                          \
} while (0)

  LOADC(bufA, start);
  LOADC(bufB, start + 8);
  for (int tc = start; tc < end; tc += 16) {
    STEP8(bufA, tc);
    LOADC(bufA, tc + 16);      // ~8 steps ahead of use
    STEP8(bufB, tc + 8);
    LOADC(bufB, tc + 24);
  }
#undef LOADC
#undef STEP8
}

extern "C" void kernel_launch(void* const* d_in, const int* in_sizes, int n_in,
                              void* d_out, int out_size, void* d_ws, size_t ws_size,
                              hipStream_t stream) {
  const float* x      = (const float*)d_in[0];
  const int*   ridx   = (const int*)  d_in[1];
  const float* W_ih   = (const float*)d_in[2];
  const float* W_hh   = (const float*)d_in[3];
  const float* b_ih   = (const float*)d_in[4];
  const float* b_hh   = (const float*)d_in[5];
  const float* W_proj = (const float*)d_in[6];
  const float* b_proj = (const float*)d_in[7];
  float* out = (float*)d_out;

  float* xg  = (float*)d_ws;                          // T*B*32 f32 = 128 MiB
  char*  aux = (char*)d_ws + (size_t)134217728;       // after xg
  s16x8* whi = (s16x8*)aux;                           // 512 * 16 B = 8 KiB
  s16x8* wlo = whi + 512;                             // 8 KiB
  float* bo  = (float*)(wlo + 512);                   // 32 floats

  prep_kernel<<<1, 64, 0, stream>>>(W_ih, b_ih, b_hh, whi, wlo, bo);
  gates_kernel<<<(TT * BB) / 64, 256, 0, stream>>>(x, whi, wlo, bo, xg);
  rnn_kernel<<<dim3(33, 32), 64, 0, stream>>>(xg, ridx, W_hh, W_proj, b_proj, out);
}